// Round 1
// 101.566 us; speedup vs baseline: 1.0013x; 1.0013x over previous
//
#include <hip/hip_runtime.h>

// IntraSentenceAttention, MFMA bf16 + workspace pre-pass + global_load_lds.
// out[b,i,:] = m_i * sum_j e_ij x[b,j,:] / (sum_j e_ij + EPS)
//   e_ij = exp(dot(x_i,x_j) + min(i-j,10)) * m_j
// B=32, T=1024, D=128. Scores <= ~12.3+10 -> no online rescale needed.
//
// Round-6 change: 16x16x32 -> 32x32x16 MFMA (2x MACs per 16B LDS fragment
// -> LDS-pipe traffic per FLOP halved; prior kernel was ~47% LDS-pipe-bound).
// Waves restructured 4x16-rows -> (wi,wj) 2x2: each wave owns 32 i-rows and
// one 32-j half-tile; cross-wj O^T/dsum reduction once at the end via LDS
// (reuses Kb space). DMA/swizzle/double-buffer/1-barrier-per-tile kept from
// the verified round-5 kernel. Harness poisons d_ws every iter (~44 us fill)
// regardless -> ws use stays free.

typedef __bf16 bf16x8 __attribute__((ext_vector_type(8)));
typedef __bf16 bf16x4 __attribute__((ext_vector_type(4)));
typedef float  f32x4  __attribute__((ext_vector_type(4)));
typedef float  f32x16 __attribute__((ext_vector_type(16)));

typedef const __attribute__((address_space(1))) void* gptr_t;
typedef __attribute__((address_space(3))) void* lptr_t;

constexpr int Tn = 1024;
constexpr int Dn = 128;
constexpr int BM = 64;
constexpr int BN = 64;
constexpr int NT = Tn / BN;      // 16 j-tiles
constexpr float EPSF = 1e-7f;

// ==================== prep: x fp32 -> Xb bf16, XbT bf16 ====================
// grid (Tn/64, B), 256 threads. tile[64][129]: +1 pad breaks column-read
// conflicts; 129 covers full 128-d rows.
__global__ __launch_bounds__(256)
void prep(const float* __restrict__ x, __bf16* __restrict__ Xb,
          __bf16* __restrict__ XbT) {
    __shared__ float tile[64][129];
    const int b = blockIdx.y, t0 = blockIdx.x * 64, t = threadIdx.x;
    #pragma unroll
    for (int k = 0; k < 8; ++k) {
        int cid = t + k * 256;                 // 2048 units: 64 rows x 32 f4-chunks
        int r = cid >> 5, c4 = cid & 31;
        float4 v = *(const float4*)(x + (size_t)(b * Tn + t0 + r) * Dn + c4 * 4);
        bf16x4 bv;
        bv[0] = (__bf16)v.x; bv[1] = (__bf16)v.y; bv[2] = (__bf16)v.z; bv[3] = (__bf16)v.w;
        *(bf16x4*)(Xb + (size_t)(b * Tn + t0 + r) * Dn + c4 * 4) = bv;
        *(float4*)&tile[r][c4 * 4] = v;
    }
    __syncthreads();
    #pragma unroll
    for (int k = 0; k < 2; ++k) {
        int cid = t + k * 256;                 // 512 units: 128 d x 4 t-chunks(16)
        int dd = cid >> 2, tq = cid & 3;
        bf16x8 v0, v1;
        #pragma unroll
        for (int j = 0; j < 8; ++j) v0[j] = (__bf16)tile[tq * 16 + j][dd];
        #pragma unroll
        for (int j = 0; j < 8; ++j) v1[j] = (__bf16)tile[tq * 16 + 8 + j][dd];
        __bf16* o = XbT + (size_t)(b * Dn + dd) * Tn + t0 + tq * 16;
        *(bf16x8*)o = v0;
        *(bf16x8*)(o + 8) = v1;
    }
}

// ============================ main MFMA kernel ============================
// LDS: Kb [j(64)][d(128)]: 16B-chunk slot s of row r holds chunk s^(r&15)
//      KTb[d(128)][j(64)]: slot s of row d holds chunk s^(d&7)
//      Pb [i(64)][j(64)] : slot s of row i at s^(i&7)  (wave-private rows)
// Waves: w = wi + 2*wj; wave owns i-rows [i0+32wi, i0+32wi+32) x j-half wj.
__global__ __launch_bounds__(256, 2)
void attn_mfma(const __bf16* __restrict__ Xb, const __bf16* __restrict__ XbT,
               const int* __restrict__ mask, float* __restrict__ out) {
    __shared__ __align__(16) __bf16 Kb[2][64 * 128];    // 32 KB (reused as red)
    __shared__ __align__(16) __bf16 KTb[2][128 * 64];   // 32 KB (reused as dsh)
    __shared__ __align__(16) __bf16 Pb[64 * 64];        // 8 KB
    __shared__ __align__(16) float mbias[Tn];           // 4 KB

    const int t = threadIdx.x, w = t >> 6, l = t & 63;
    const int lm = l & 31, hi = l >> 5;
    const int wi = w & 1, wj = w >> 1;
    const int bid = blockIdx.x;
    const int b = bid & 31, i0 = (bid >> 5) * BM;   // bid%8==b%8: XCD L2 affinity
    const __bf16* xb  = Xb  + (size_t)b * Tn * Dn;
    const __bf16* xtb = XbT + (size_t)b * Dn * Tn;

    // mask bias for all 1024 j, once
    for (int k = t; k < Tn; k += 256)
        mbias[k] = (mask[b * Tn + k] != 0) ? 0.f : -1e5f;

    // Q B-frags in registers all kernel: aq[kt] = Q[i_lane][kt*16 + hi*8 + j]
    const int i_lane = i0 + 32 * wi + lm;
    bf16x8 aq[8];
    {
        const __bf16* qrow = xb + (size_t)i_lane * Dn + hi * 8;
        #pragma unroll
        for (int kt = 0; kt < 8; ++kt) aq[kt] = *(const bf16x8*)(qrow + kt * 16);
    }

    // DMA one 64-row tile into buffers bs (4 waves x (4+4) calls).
    // Kb call k: lane i -> row k*4 + (i>>4), slot i&15, source chunk slot^(row&15)
    // KTb call k: lane i -> d-row k*8 + (i>>3), slot i&7, source chunk slot^(d&7)
    auto dma_tile = [&](int j0, int bs) {
        #pragma unroll
        for (int q = 0; q < 4; ++q) {
            const int k = w * 4 + q;
            const int rl = k * 4 + (l >> 4);
            const int c  = (l & 15) ^ (rl & 15);
            const __bf16* g = xb + (size_t)(j0 + rl) * Dn + c * 8;
            __builtin_amdgcn_global_load_lds((gptr_t)g, (lptr_t)(&Kb[bs][k * 512]),
                                             16, 0, 0);
        }
        #pragma unroll
        for (int q = 0; q < 4; ++q) {
            const int k = w * 4 + q;
            const int d = k * 8 + (l >> 3);
            const int c = (l & 7) ^ (d & 7);
            const __bf16* g = xtb + (size_t)d * Tn + j0 + c * 8;
            __builtin_amdgcn_global_load_lds((gptr_t)g, (lptr_t)(&KTb[bs][k * 512]),
                                             16, 0, 0);
        }
    };

    dma_tile(0, 0);

    f32x16 acc[4];                           // O^T: d-block db, 32x32 C each
    #pragma unroll
    for (int db = 0; db < 4; ++db)
        #pragma unroll
        for (int r = 0; r < 16; ++r) acc[db][r] = 0.f;
    float dsum = 0.f;                        // den partial (own wj half, own hi)
    const float fi = (float)i_lane;
    const int prow = 32 * wi + lm;           // Pb row (tile-local i)

    __syncthreads();   // tile 0 DMA drained (vmcnt) + mbias visible

    for (int jt = 0; jt < NT; ++jt) {
        const int bs = jt & 1, j0 = jt * BN;
        // DMA next tile into the other buffer; in flight across this compute
        const int jn = (jt + 1 < NT) ? (jt + 1) * BN : j0;
        dma_tile(jn, bs ^ 1);

        // ---- stage 1: S^T = K*Q^T (A=Kb rows of own j-half, B=Q frags) ----
        f32x16 cs;
        #pragma unroll
        for (int r = 0; r < 16; ++r) cs[r] = 0.f;
        const int arow = 32 * wj + lm;       // tile-local j row, arow&31==lm
        #pragma unroll
        for (int kt = 0; kt < 8; ++kt) {
            const int slot = (2 * kt + hi) ^ (arow & 15);
            bf16x8 av = *(const bf16x8*)(&Kb[bs][arow * 128 + slot * 8]);
            cs = __builtin_amdgcn_mfma_f32_32x32x16_bf16(av, aq[kt], cs, 0, 0, 0);
        }
        // C layout: col=i=lm (fixed), row=j_local=(r&3)+8*(r>>2)+4*hi
        // exp + pack 4-groups -> Pb (wave-private rows, chunk 4*wj+g, half hi)
        #pragma unroll
        for (int g = 0; g < 4; ++g) {
            const int jbase = j0 + 32 * wj + 8 * g + 4 * hi;
            const float4 m4 = *(const float4*)&mbias[jbase];
            const float base = fi - (float)jbase;
            bf16x4 pv;
            #pragma unroll
            for (int r3 = 0; r3 < 4; ++r3) {
                float e = __expf(cs[4 * g + r3] + fminf(base - (float)r3, 10.f)
                                 + ((const float*)&m4)[r3]);
                dsum += e;
                pv[r3] = (__bf16)e;
            }
            const int slot = (4 * wj + g) ^ (prow & 7);
            *(bf16x4*)(&Pb[prow * 64 + slot * 8 + hi * 4]) = pv;
        }

        // ---- stage 2: O^T += K^T * P^T (A=KTb rows, B=P frags, own wj) ----
        #pragma unroll
        for (int k2 = 0; k2 < 2; ++k2) {
            const int pslot = (4 * wj + 2 * k2 + hi) ^ (prow & 7);
            bf16x8 bp = *(const bf16x8*)(&Pb[prow * 64 + pslot * 8]);
            #pragma unroll
            for (int db = 0; db < 4; ++db) {
                const int d = 32 * db + lm;
                const int slot = (4 * wj + 2 * k2 + hi) ^ (d & 7);
                bf16x8 av = *(const bf16x8*)(&KTb[bs][d * 64 + slot * 8]);
                acc[db] = __builtin_amdgcn_mfma_f32_32x32x16_bf16(av, bp, acc[db],
                                                                  0, 0, 0);
            }
        }
        __syncthreads();   // next buffer's DMA drained; this buffer reusable
    }

    // ---- epilogue: fold hi, cross-wj reduce via LDS (reuse Kb), store ----
    dsum += __shfl_xor(dsum, 32);
    float* red = (float*)&Kb[0][0];          // 16 slots x 128 lanes x f32x4 = 32 KB
    float* dsh = (float*)&KTb[0][0];         // 128 floats
    if (wj == 1) {
        #pragma unroll
        for (int db = 0; db < 4; ++db)
            #pragma unroll
            for (int g = 0; g < 4; ++g) {
                float4 v;
                v.x = acc[db][4 * g + 0]; v.y = acc[db][4 * g + 1];
                v.z = acc[db][4 * g + 2]; v.w = acc[db][4 * g + 3];
                *(float4*)&red[((db * 4 + g) * 128 + wi * 64 + l) * 4] = v;
            }
        dsh[wi * 64 + l] = dsum;
    }
    __syncthreads();
    if (wj == 0) {
        dsum += dsh[wi * 64 + l];
        const float mi = (mask[b * Tn + i_lane] != 0) ? 1.f : 0.f;
        const float inv = mi / (dsum + EPSF);
        float* orow = out + (size_t)(b * Tn + i_lane) * Dn;
        // O^T: col=i=lm, rows d = 32*db + (r&3) + 8*(r>>2) + 4*hi
        #pragma unroll
        for (int db = 0; db < 4; ++db)
            #pragma unroll
            for (int g = 0; g < 4; ++g) {
                const float4 v = *(const float4*)&red[((db * 4 + g) * 128
                                                       + wi * 64 + l) * 4];
                float4 o;
                o.x = (acc[db][4 * g + 0] + v.x) * inv;
                o.y = (acc[db][4 * g + 1] + v.y) * inv;
                o.z = (acc[db][4 * g + 2] + v.z) * inv;
                o.w = (acc[db][4 * g + 3] + v.w) * inv;
                *(float4*)(orow + 32 * db + 8 * g + 4 * hi) = o;
            }
    }
}

// ===================== fallback fp32 kernel (no ws) =====================
constexpr int KS = 128;
__device__ __forceinline__ int swz(int row, int c4) { return (c4 ^ ((row >> 2) & 7)); }

__global__ __launch_bounds__(256, 2)
void attn_fused(const float* __restrict__ x, const int* __restrict__ mask,
                float* __restrict__ out) {
    __shared__ float Qs[BM * KS];
    __shared__ float Ks[BN * KS];
    __shared__ float Pt[BN * BM];
    __shared__ float mks[BN];
    const int t = threadIdx.x, b = blockIdx.y, i0 = blockIdx.x * BM;
    const float* xb = x + (size_t)b * Tn * Dn;
    #pragma unroll
    for (int k = 0; k < 8; ++k) {
        int idx = t + k * 256, r = idx >> 5, c4 = idx & 31;
        float4 v = *(const float4*)(xb + (size_t)(i0 + r) * Dn + c4 * 4);
        *(float4*)(&Qs[r * KS + swz(r, c4) * 4]) = v;
    }
    const int sx = t & 15, sy = t >> 4, pc = t & 15, pr = t >> 4;
    float acc[4][8], den[4] = {0.f, 0.f, 0.f, 0.f};
    #pragma unroll
    for (int r = 0; r < 4; ++r)
        #pragma unroll
        for (int c = 0; c < 8; ++c) acc[r][c] = 0.f;
    for (int jt = 0; jt < Tn / BN; ++jt) {
        const int j0 = jt * BN;
        __syncthreads();
        #pragma unroll
        for (int k = 0; k < 8; ++k) {
            int idx = t + k * 256, r = idx >> 5, c4 = idx & 31;
            float4 v = *(const float4*)(xb + (size_t)(j0 + r) * Dn + c4 * 4);
            *(float4*)(&Ks[r * KS + swz(r, c4) * 4]) = v;
        }
        if (t < BN) mks[t] = (mask[b * Tn + j0 + t] != 0) ? 1.0f : 0.0f;
        __syncthreads();
        float s[4][4];
        #pragma unroll
        for (int r = 0; r < 4; ++r)
            #pragma unroll
            for (int c = 0; c < 4; ++c) s[r][c] = 0.f;
        #pragma unroll 4
        for (int d4 = 0; d4 < Dn / 4; ++d4) {
            float4 q[4], kk[4];
            #pragma unroll
            for (int r = 0; r < 4; ++r)
                q[r] = *(const float4*)(&Qs[(4 * sy + r) * KS + (d4 ^ (sy & 7)) * 4]);
            #pragma unroll
            for (int c = 0; c < 4; ++c)
                kk[c] = *(const float4*)(&Ks[(4 * sx + c) * KS + (d4 ^ (sx & 7)) * 4]);
            #pragma unroll
            for (int r = 0; r < 4; ++r)
                #pragma unroll
                for (int c = 0; c < 4; ++c)
                    s[r][c] += q[r].x * kk[c].x + q[r].y * kk[c].y
                             + q[r].z * kk[c].z + q[r].w * kk[c].w;
        }
        #pragma unroll
        for (int r = 0; r < 4; ++r) {
            int i = i0 + 4 * sy + r;
            #pragma unroll
            for (int c = 0; c < 4; ++c) {
                int j = j0 + 4 * sx + c, di = i - j;
                float dist = (float)(di < 10 ? di : 10);
                Pt[(4 * sx + c) * BM + (4 * sy + r)] =
                    __expf(s[r][c] + dist) * mks[4 * sx + c];
            }
        }
        __syncthreads();
        #pragma unroll 4
        for (int j = 0; j < BN; ++j) {
            float4 p4 = *(const float4*)(&Pt[j * BM + 4 * pr]);
            int sw = (j >> 2) & 7;
            float4 k0 = *(const float4*)(&Ks[j * KS + ((2 * pc)     ^ sw) * 4]);
            float4 k1 = *(const float4*)(&Ks[j * KS + ((2 * pc + 1) ^ sw) * 4]);
            float pv[4] = {p4.x, p4.y, p4.z, p4.w};
            #pragma unroll
            for (int r = 0; r < 4; ++r) {
                den[r] += pv[r];
                acc[r][0] += pv[r] * k0.x; acc[r][1] += pv[r] * k0.y;
                acc[r][2] += pv[r] * k0.z; acc[r][3] += pv[r] * k0.w;
                acc[r][4] += pv[r] * k1.x; acc[r][5] += pv[r] * k1.y;
                acc[r][6] += pv[r] * k1.z; acc[r][7] += pv[r] * k1.w;
            }
        }
    }
    const int* mrow = mask + (size_t)b * Tn + i0;
    float* ob = out + ((size_t)b * Tn + i0) * Dn;
    #pragma unroll
    for (int r = 0; r < 4; ++r) {
        int row = 4 * pr + r;
        float mi = (mrow[row] != 0) ? 1.0f : 0.0f;
        float inv = mi / (den[r] + EPSF);
        float4 o0, o1;
        o0.x = acc[r][0] * inv; o0.y = acc[r][1] * inv;
        o0.z = acc[r][2] * inv; o0.w = acc[r][3] * inv;
        o1.x = acc[r][4] * inv; o1.y = acc[r][5] * inv;
        o1.z = acc[r][6] * inv; o1.w = acc[r][7] * inv;
        *(float4*)(&ob[(size_t)row * Dn + 8 * pc    ]) = o0;
        *(float4*)(&ob[(size_t)row * Dn + 8 * pc + 4]) = o1;
    }
}

// ============================ launch ============================
extern "C" void kernel_launch(void* const* d_in, const int* in_sizes, int n_in,
                              void* d_out, int out_size, void* d_ws, size_t ws_size,
                              hipStream_t stream) {
    const float* x    = (const float*)d_in[0];
    const int*   mask = (const int*)d_in[1];
    float*       out  = (float*)d_out;
    const int nx = in_sizes[0];              // B*T*D
    const int B  = in_sizes[1] / Tn;         // 32

    const size_t need = (size_t)nx * 2 * 2;  // Xb + XbT bf16
    if (ws_size >= need) {
        __bf16* Xb  = (__bf16*)d_ws;
        __bf16* XbT = Xb + nx;
        dim3 pg(Tn / 64, B);
        prep<<<pg, 256, 0, stream>>>(x, Xb, XbT);
        attn_mfma<<<B * (Tn / BM), 256, 0, stream>>>(Xb, XbT, mask, out);
    } else {
        dim3 grid(Tn / BM, B);
        attn_fused<<<grid, 256, 0, stream>>>(x, mask, out);
    }
}

// Round 2
// 99.403 us; speedup vs baseline: 1.0231x; 1.0218x over previous
//
#include <hip/hip_runtime.h>

// IntraSentenceAttention, MFMA bf16 + workspace pre-pass + global_load_lds.
// out[b,i,:] = m_i * sum_j e_ij x[b,j,:] / (sum_j e_ij + EPS)
//   e_ij = exp(dot(x_i,x_j) + min(i-j,10)) * m_j
// B=32, T=1024, D=128. Scores <= ~12.3+10 -> no online rescale needed.
//
// Round-7 change: BM 64 -> 128 (256 blocks x 512 thr, 8 waves = 4 wi x 2 wj).
// Theory: attn (~42 us) is READ-VOLUME bound: 512 blocks x 512 KB panel
// re-reads = 268 MB/iter ~ 45 us at ~6 TB/s; MFMA/LDS restructure (round-6)
// was exactly neutral, consistent with memory-bound. BM=128 halves re-reads
// (134 MB). Per-wave per-tile work unchanged (same MFMA/exp/LDS counts),
// isolating the memory variable. LDS 84 KB carved; cross-wj reduce aliases
// Kb/KTb after final barrier. Harness poisons d_ws every iter (~45 us fill,
// fixed cost) -> ws use stays free.

typedef __bf16 bf16x8 __attribute__((ext_vector_type(8)));
typedef __bf16 bf16x4 __attribute__((ext_vector_type(4)));
typedef float  f32x4  __attribute__((ext_vector_type(4)));
typedef float  f32x16 __attribute__((ext_vector_type(16)));

typedef const __attribute__((address_space(1))) void* gptr_t;
typedef __attribute__((address_space(3))) void* lptr_t;

constexpr int Tn = 1024;
constexpr int Dn = 128;
constexpr int BM = 128;          // i-rows per block (round-7: was 64)
constexpr int BN = 64;           // j-rows per tile
constexpr int NT = Tn / BN;      // 16 j-tiles
constexpr float EPSF = 1e-7f;

// ==================== prep: x fp32 -> Xb bf16, XbT bf16 ====================
// grid (Tn/64, B), 256 threads. tile[64][129]: +1 pad breaks column-read
// conflicts; 129 covers full 128-d rows.
__global__ __launch_bounds__(256)
void prep(const float* __restrict__ x, __bf16* __restrict__ Xb,
          __bf16* __restrict__ XbT) {
    __shared__ float tile[64][129];
    const int b = blockIdx.y, t0 = blockIdx.x * 64, t = threadIdx.x;
    #pragma unroll
    for (int k = 0; k < 8; ++k) {
        int cid = t + k * 256;                 // 2048 units: 64 rows x 32 f4-chunks
        int r = cid >> 5, c4 = cid & 31;
        float4 v = *(const float4*)(x + (size_t)(b * Tn + t0 + r) * Dn + c4 * 4);
        bf16x4 bv;
        bv[0] = (__bf16)v.x; bv[1] = (__bf16)v.y; bv[2] = (__bf16)v.z; bv[3] = (__bf16)v.w;
        *(bf16x4*)(Xb + (size_t)(b * Tn + t0 + r) * Dn + c4 * 4) = bv;
        *(float4*)&tile[r][c4 * 4] = v;
    }
    __syncthreads();
    #pragma unroll
    for (int k = 0; k < 2; ++k) {
        int cid = t + k * 256;                 // 512 units: 128 d x 4 t-chunks(16)
        int dd = cid >> 2, tq = cid & 3;
        bf16x8 v0, v1;
        #pragma unroll
        for (int j = 0; j < 8; ++j) v0[j] = (__bf16)tile[tq * 16 + j][dd];
        #pragma unroll
        for (int j = 0; j < 8; ++j) v1[j] = (__bf16)tile[tq * 16 + 8 + j][dd];
        __bf16* o = XbT + (size_t)(b * Dn + dd) * Tn + t0 + tq * 16;
        *(bf16x8*)o = v0;
        *(bf16x8*)(o + 8) = v1;
    }
}

// ============================ main MFMA kernel ============================
// LDS layout (carved from one 84 KB block):
//   Kb [2][j(64)][d(128)]: 16B-chunk slot s of row r holds chunk s^(r&15)
//   KTb[2][d(128)][j(64)]: slot s of row d holds chunk s^(d&7)
//   Pb [i(128)][j(64)]   : slot s of row i at s^(i&7)  (wave-private rows)
//   mbias[1024] float
// Waves: w = wi + 4*wj; wave owns i-rows [i0+32wi, i0+32wi+32) x j-half wj.
__global__ __launch_bounds__(512, 2)
void attn_mfma(const __bf16* __restrict__ Xb, const __bf16* __restrict__ XbT,
               const int* __restrict__ mask, float* __restrict__ out) {
    __shared__ __align__(16) unsigned char smem[86016];   // 84 KB
    __bf16* Kb    = (__bf16*)smem;                 // 2 x 8192 elems (32 KB)
    __bf16* KTb   = (__bf16*)(smem + 32768);       // 2 x 8192 elems (32 KB)
    __bf16* Pb    = (__bf16*)(smem + 65536);       // 8192 elems (16 KB)
    float*  mbias = (float*)(smem + 81920);        // 1024 floats (4 KB)

    const int t = threadIdx.x, w = t >> 6, l = t & 63;
    const int lm = l & 31, hi = l >> 5;
    const int wi = w & 3, wj = w >> 2;
    const int bid = blockIdx.x;
    const int b = bid & 31, i0 = (bid >> 5) * BM;   // bid%8==b%8: XCD L2 affinity
    const __bf16* xb  = Xb  + (size_t)b * Tn * Dn;
    const __bf16* xtb = XbT + (size_t)b * Dn * Tn;

    // mask bias for all 1024 j, once
    for (int k = t; k < Tn; k += 512)
        mbias[k] = (mask[b * Tn + k] != 0) ? 0.f : -1e5f;

    // Q B-frags in registers all kernel: aq[kt] = Q[i_lane][kt*16 + hi*8 + j]
    const int i_lane = i0 + 32 * wi + lm;
    bf16x8 aq[8];
    {
        const __bf16* qrow = xb + (size_t)i_lane * Dn + hi * 8;
        #pragma unroll
        for (int kt = 0; kt < 8; ++kt) aq[kt] = *(const bf16x8*)(qrow + kt * 16);
    }

    // DMA one 64-row tile into buffer bs (8 waves x (2+2) calls, 1 KB each).
    // Kb call k: lane i -> row k*4 + (i>>4), slot i&15, source chunk slot^(row&15)
    // KTb call k: lane i -> d-row k*8 + (i>>3), slot i&7, source chunk slot^(d&7)
    auto dma_tile = [&](int j0, int bs) {
        #pragma unroll
        for (int q = 0; q < 2; ++q) {
            const int k = w * 2 + q;                       // 0..15
            const int rl = k * 4 + (l >> 4);
            const int c  = (l & 15) ^ (rl & 15);
            const __bf16* g = xb + (size_t)(j0 + rl) * Dn + c * 8;
            __builtin_amdgcn_global_load_lds((gptr_t)g,
                (lptr_t)(Kb + bs * 8192 + k * 512), 16, 0, 0);
        }
        #pragma unroll
        for (int q = 0; q < 2; ++q) {
            const int k = w * 2 + q;                       // 0..15
            const int d = k * 8 + (l >> 3);
            const int c = (l & 7) ^ (d & 7);
            const __bf16* g = xtb + (size_t)d * Tn + j0 + c * 8;
            __builtin_amdgcn_global_load_lds((gptr_t)g,
                (lptr_t)(KTb + bs * 8192 + k * 512), 16, 0, 0);
        }
    };

    dma_tile(0, 0);

    f32x16 acc[4];                           // O^T: d-block db, 32x32 C each
    #pragma unroll
    for (int db = 0; db < 4; ++db)
        #pragma unroll
        for (int r = 0; r < 16; ++r) acc[db][r] = 0.f;
    float dsum = 0.f;                        // den partial (own wj half, own hi)
    const float fi = (float)i_lane;
    const int prow = 32 * wi + lm;           // Pb row (tile-local i), 0..127

    __syncthreads();   // tile 0 DMA drained (vmcnt) + mbias visible

    for (int jt = 0; jt < NT; ++jt) {
        const int bs = jt & 1, j0 = jt * BN;
        // DMA next tile into the other buffer; in flight across this compute
        if (jt + 1 < NT) dma_tile((jt + 1) * BN, bs ^ 1);

        // ---- stage 1: S^T = K*Q^T (A=Kb rows of own j-half, B=Q frags) ----
        f32x16 cs;
        #pragma unroll
        for (int r = 0; r < 16; ++r) cs[r] = 0.f;
        const int arow = 32 * wj + lm;       // tile-local j row, arow&31==lm
        #pragma unroll
        for (int kt = 0; kt < 8; ++kt) {
            const int slot = (2 * kt + hi) ^ (arow & 15);
            bf16x8 av = *(const bf16x8*)(Kb + bs * 8192 + arow * 128 + slot * 8);
            cs = __builtin_amdgcn_mfma_f32_32x32x16_bf16(av, aq[kt], cs, 0, 0, 0);
        }
        // C layout: col=i=lm (fixed), row=j_local=(r&3)+8*(r>>2)+4*hi
        // exp + pack 4-groups -> Pb (wave-private rows, chunk 4*wj+g, half hi)
        #pragma unroll
        for (int g = 0; g < 4; ++g) {
            const int jbase = j0 + 32 * wj + 8 * g + 4 * hi;
            const float4 m4 = *(const float4*)&mbias[jbase];
            const float base = fi - (float)jbase;
            bf16x4 pv;
            #pragma unroll
            for (int r3 = 0; r3 < 4; ++r3) {
                float e = __expf(cs[4 * g + r3] + fminf(base - (float)r3, 10.f)
                                 + ((const float*)&m4)[r3]);
                dsum += e;
                pv[r3] = (__bf16)e;
            }
            const int slot = (4 * wj + g) ^ (prow & 7);
            *(bf16x4*)(Pb + prow * 64 + slot * 8 + hi * 4) = pv;
        }

        // ---- stage 2: O^T += K^T * P^T (A=KTb rows, B=P frags, own wj) ----
        #pragma unroll
        for (int k2 = 0; k2 < 2; ++k2) {
            const int pslot = (4 * wj + 2 * k2 + hi) ^ (prow & 7);
            bf16x8 bp = *(const bf16x8*)(Pb + prow * 64 + pslot * 8);
            #pragma unroll
            for (int db = 0; db < 4; ++db) {
                const int d = 32 * db + lm;
                const int slot = (4 * wj + 2 * k2 + hi) ^ (d & 7);
                bf16x8 av = *(const bf16x8*)(KTb + bs * 8192 + d * 64 + slot * 8);
                acc[db] = __builtin_amdgcn_mfma_f32_32x32x16_bf16(av, bp, acc[db],
                                                                  0, 0, 0);
            }
        }
        __syncthreads();   // next buffer's DMA drained; this buffer reusable
    }

    // ---- epilogue: fold hi, cross-wj reduce via LDS (alias Kb/KTb), store ----
    dsum += __shfl_xor(dsum, 32);
    float* red = (float*)smem;               // 16 x 256 x f32x4 = 64 KB
    float* dsh = (float*)(smem + 65536);     // 256 floats
    if (wj == 1) {
        #pragma unroll
        for (int db = 0; db < 4; ++db)
            #pragma unroll
            for (int g = 0; g < 4; ++g) {
                float4 v;
                v.x = acc[db][4 * g + 0]; v.y = acc[db][4 * g + 1];
                v.z = acc[db][4 * g + 2]; v.w = acc[db][4 * g + 3];
                *(float4*)&red[((db * 4 + g) * 256 + wi * 64 + l) * 4] = v;
            }
        dsh[wi * 64 + l] = dsum;
    }
    __syncthreads();
    if (wj == 0) {
        dsum += dsh[wi * 64 + l];
        const float mi = (mask[b * Tn + i_lane] != 0) ? 1.f : 0.f;
        const float inv = mi / (dsum + EPSF);
        float* orow = out + (size_t)(b * Tn + i_lane) * Dn;
        // O^T: col=i=lm, rows d = 32*db + (r&3) + 8*(r>>2) + 4*hi
        #pragma unroll
        for (int db = 0; db < 4; ++db)
            #pragma unroll
            for (int g = 0; g < 4; ++g) {
                const float4 v = *(const float4*)&red[((db * 4 + g) * 256
                                                       + wi * 64 + l) * 4];
                float4 o;
                o.x = (acc[db][4 * g + 0] + v.x) * inv;
                o.y = (acc[db][4 * g + 1] + v.y) * inv;
                o.z = (acc[db][4 * g + 2] + v.z) * inv;
                o.w = (acc[db][4 * g + 3] + v.w) * inv;
                *(float4*)(orow + 32 * db + 8 * g + 4 * hi) = o;
            }
    }
}

// ===================== fallback fp32 kernel (no ws) =====================
constexpr int FBM = 64;
constexpr int FBN = 64;
constexpr int KS = 128;
__device__ __forceinline__ int swz(int row, int c4) { return (c4 ^ ((row >> 2) & 7)); }

__global__ __launch_bounds__(256, 2)
void attn_fused(const float* __restrict__ x, const int* __restrict__ mask,
                float* __restrict__ out) {
    __shared__ float Qs[FBM * KS];
    __shared__ float Ks[FBN * KS];
    __shared__ float Pt[FBN * FBM];
    __shared__ float mks[FBN];
    const int t = threadIdx.x, b = blockIdx.y, i0 = blockIdx.x * FBM;
    const float* xb = x + (size_t)b * Tn * Dn;
    #pragma unroll
    for (int k = 0; k < 8; ++k) {
        int idx = t + k * 256, r = idx >> 5, c4 = idx & 31;
        float4 v = *(const float4*)(xb + (size_t)(i0 + r) * Dn + c4 * 4);
        *(float4*)(&Qs[r * KS + swz(r, c4) * 4]) = v;
    }
    const int sx = t & 15, sy = t >> 4, pc = t & 15, pr = t >> 4;
    float acc[4][8], den[4] = {0.f, 0.f, 0.f, 0.f};
    #pragma unroll
    for (int r = 0; r < 4; ++r)
        #pragma unroll
        for (int c = 0; c < 8; ++c) acc[r][c] = 0.f;
    for (int jt = 0; jt < Tn / FBN; ++jt) {
        const int j0 = jt * FBN;
        __syncthreads();
        #pragma unroll
        for (int k = 0; k < 8; ++k) {
            int idx = t + k * 256, r = idx >> 5, c4 = idx & 31;
            float4 v = *(const float4*)(xb + (size_t)(j0 + r) * Dn + c4 * 4);
            *(float4*)(&Ks[r * KS + swz(r, c4) * 4]) = v;
        }
        if (t < FBN) mks[t] = (mask[b * Tn + j0 + t] != 0) ? 1.0f : 0.0f;
        __syncthreads();
        float s[4][4];
        #pragma unroll
        for (int r = 0; r < 4; ++r)
            #pragma unroll
            for (int c = 0; c < 4; ++c) s[r][c] = 0.f;
        #pragma unroll 4
        for (int d4 = 0; d4 < Dn / 4; ++d4) {
            float4 q[4], kk[4];
            #pragma unroll
            for (int r = 0; r < 4; ++r)
                q[r] = *(const float4*)(&Qs[(4 * sy + r) * KS + (d4 ^ (sy & 7)) * 4]);
            #pragma unroll
            for (int c = 0; c < 4; ++c)
                kk[c] = *(const float4*)(&Ks[(4 * sx + c) * KS + (d4 ^ (sx & 7)) * 4]);
            #pragma unroll
            for (int r = 0; r < 4; ++r)
                #pragma unroll
                for (int c = 0; c < 4; ++c)
                    s[r][c] += q[r].x * kk[c].x + q[r].y * kk[c].y
                             + q[r].z * kk[c].z + q[r].w * kk[c].w;
        }
        #pragma unroll
        for (int r = 0; r < 4; ++r) {
            int i = i0 + 4 * sy + r;
            #pragma unroll
            for (int c = 0; c < 4; ++c) {
                int j = j0 + 4 * sx + c, di = i - j;
                float dist = (float)(di < 10 ? di : 10);
                Pt[(4 * sx + c) * FBM + (4 * sy + r)] =
                    __expf(s[r][c] + dist) * mks[4 * sx + c];
            }
        }
        __syncthreads();
        #pragma unroll 4
        for (int j = 0; j < FBN; ++j) {
            float4 p4 = *(const float4*)(&Pt[j * FBM + 4 * pr]);
            int sw = (j >> 2) & 7;
            float4 k0 = *(const float4*)(&Ks[j * KS + ((2 * pc)     ^ sw) * 4]);
            float4 k1 = *(const float4*)(&Ks[j * KS + ((2 * pc + 1) ^ sw) * 4]);
            float pv[4] = {p4.x, p4.y, p4.z, p4.w};
            #pragma unroll
            for (int r = 0; r < 4; ++r) {
                den[r] += pv[r];
                acc[r][0] += pv[r] * k0.x; acc[r][1] += pv[r] * k0.y;
                acc[r][2] += pv[r] * k0.z; acc[r][3] += pv[r] * k0.w;
                acc[r][4] += pv[r] * k1.x; acc[r][5] += pv[r] * k1.y;
                acc[r][6] += pv[r] * k1.z; acc[r][7] += pv[r] * k1.w;
            }
        }
    }
    const int* mrow = mask + (size_t)b * Tn + i0;
    float* ob = out + ((size_t)b * Tn + i0) * Dn;
    #pragma unroll
    for (int r = 0; r < 4; ++r) {
        int row = 4 * pr + r;
        float mi = (mrow[row] != 0) ? 1.0f : 0.0f;
        float inv = mi / (den[r] + EPSF);
        float4 o0, o1;
        o0.x = acc[r][0] * inv; o0.y = acc[r][1] * inv;
        o0.z = acc[r][2] * inv; o0.w = acc[r][3] * inv;
        o1.x = acc[r][4] * inv; o1.y = acc[r][5] * inv;
        o1.z = acc[r][6] * inv; o1.w = acc[r][7] * inv;
        *(float4*)(&ob[(size_t)row * Dn + 8 * pc    ]) = o0;
        *(float4*)(&ob[(size_t)row * Dn + 8 * pc + 4]) = o1;
    }
}

// ============================ launch ============================
extern "C" void kernel_launch(void* const* d_in, const int* in_sizes, int n_in,
                              void* d_out, int out_size, void* d_ws, size_t ws_size,
                              hipStream_t stream) {
    const float* x    = (const float*)d_in[0];
    const int*   mask = (const int*)d_in[1];
    float*       out  = (float*)d_out;
    const int nx = in_sizes[0];              // B*T*D
    const int B  = in_sizes[1] / Tn;         // 32

    const size_t need = (size_t)nx * 2 * 2;  // Xb + XbT bf16
    if (ws_size >= need) {
        __bf16* Xb  = (__bf16*)d_ws;
        __bf16* XbT = Xb + nx;
        dim3 pg(Tn / 64, B);
        prep<<<pg, 256, 0, stream>>>(x, Xb, XbT);
        attn_mfma<<<B * (Tn / BM), 512, 0, stream>>>(Xb, XbT, mask, out);
    } else {
        dim3 grid(Tn / FBM, B);
        attn_fused<<<grid, 256, 0, stream>>>(x, mask, out);
    }
}